// Round 3
// baseline (3054.195 us; speedup 1.0000x reference)
//
#include <hip/hip_runtime.h>

#define BLOCK 256
#define HROW 72   // LDS h-tile row stride in halves (144 B): 36 words ≡ 4 mod 32 -> 2-way (free) on b128 reads

typedef _Float16 half_t;
typedef __attribute__((ext_vector_type(8))) _Float16 half8;
typedef __attribute__((ext_vector_type(4))) float float4v;

#define L2E  1.4426950408889634f
#define L2E2 2.8853900817779268f

__device__ __forceinline__ float rcp_(float x) { return __builtin_amdgcn_rcpf(x); }
__device__ __forceinline__ float ex2(float x)  { return __builtin_amdgcn_exp2f(x); }

// ---------------- MLP kernel (near its 157TF vector roofline; untouched) ----------------
extern "C" __global__ void __launch_bounds__(BLOCK, 1) mlp_kernel(
    const float* __restrict__ inputs,
    const float* __restrict__ mW0, const float* __restrict__ mb0,
    const float* __restrict__ mW1, const float* __restrict__ mb1,
    const float* __restrict__ mW2, const float* __restrict__ mb2,
    const float* __restrict__ pW, const float* __restrict__ pb,
    float* __restrict__ out, int n)
{
    int b = blockIdx.x * BLOCK + threadIdx.x;
    if (b >= n) return;
    float f0 = inputs[(size_t)b * 18 + 16], f1 = inputs[(size_t)b * 18 + 17];
    float h0[64];
    #pragma unroll
    for (int i = 0; i < 64; ++i)
        h0[i] = fmaxf(fmaf(mW0[2 * i], f0, fmaf(mW0[2 * i + 1], f1, mb0[i])), 0.0f);
    float acc2[32];
    #pragma unroll
    for (int j = 0; j < 32; ++j) acc2[j] = mb2[j];
    #pragma unroll 2
    for (int i = 0; i < 64; ++i) {
        float a = mb1[i];
        #pragma unroll
        for (int k = 0; k < 64; ++k) a = fmaf(mW1[i * 64 + k], h0[k], a);
        a = fmaxf(a, 0.0f);
        #pragma unroll
        for (int j = 0; j < 32; ++j) acc2[j] = fmaf(mW2[j * 64 + i], a, acc2[j]);
    }
    float out0 = pb[0], out1 = pb[1];
    #pragma unroll
    for (int j = 0; j < 32; ++j) {
        out0 = fmaf(pW[256 + j], acc2[j], out0);
        out1 = fmaf(pW[288 + 256 + j], acc2[j], out1);
    }
    ((float2*)out)[b] = make_float2(out0, out1);
}

// ---------------- weight fragment setup (per layer) ----------------
__device__ __forceinline__ void setup_weights(
    const float* __restrict__ Wih, const float* __restrict__ Whh,
    const float* __restrict__ bih, const float* __restrict__ bhh,
    int quad, int jcol,
    half8 Bf[4][2], float wih_v[4], float bias_v[4])
{
    const float gscale[4] = {L2E, L2E, L2E2, L2E};
    #pragma unroll
    for (int gg = 0; gg < 4; ++gg) {
        const int nrow = gg * 64 + jcol;
        const float s = gscale[gg];
        #pragma unroll
        for (int kf = 0; kf < 2; ++kf) {
            const float4* p = (const float4*)(Whh + nrow * 64 + kf * 32 + quad * 8);
            float4 w0 = p[0], w1 = p[1];
            Bf[gg][kf] = half8{(half_t)(w0.x * s), (half_t)(w0.y * s), (half_t)(w0.z * s), (half_t)(w0.w * s),
                               (half_t)(w1.x * s), (half_t)(w1.y * s), (half_t)(w1.z * s), (half_t)(w1.w * s)};
        }
        wih_v[gg]  = Wih[nrow] * s;
        bias_v[gg] = (bih[nrow] + bhh[nrow]) * s;
    }
}

// ---------------- t=0 init (per layer; h=c=0), no barrier inside ----------------
__device__ __forceinline__ void lstm_init(
    const float* __restrict__ xt, const float wih_v[4], const float bias_v[4],
    half_t* __restrict__ buf0, int quad, int jcol, float4v cst[4])
{
    #pragma unroll
    for (int mt = 0; mt < 4; ++mt) {
        float4v x4 = *(const float4v*)&xt[mt * 16 + quad * 4];
        #pragma unroll
        for (int reg = 0; reg < 4; ++reg) {
            float Bi = ex2(fmaf(x4[reg], wih_v[0], bias_v[0]));
            float Bg = ex2(fmaf(x4[reg], wih_v[2], bias_v[2]));
            float Bo = ex2(fmaf(x4[reg], wih_v[3], bias_v[3]));
            float cn = fmaf(Bi, Bg, -Bi) * rcp_((1.0f + Bi) * (1.0f + Bg));
            cst[mt][reg] = cn;
            float Cc = ex2(cn * L2E2);
            float hv = fmaf(Bo, Cc, -Bo) * rcp_((1.0f + Bo) * (1.0f + Cc));
            buf0[(mt * 16 + quad * 4 + reg) * HROW + jcol] = (half_t)hv;
        }
    }
}

// ---------------- fused both-layer LSTM step ----------------
// Both independent LSTMs advance one timestep per call: 2x independent
// MFMA+epilogue chains per mt to fill trans latency at 2 waves/SIMD, and one
// barrier per step instead of two. LAST folds BOTH projections and does a
// single merged 16-lane shuffle reduce.
template <bool LAST>
__device__ __forceinline__ void lstm_step2(
    const float* __restrict__ xtA, const float* __restrict__ xtB,
    const half_t* __restrict__ srcA, half_t* __restrict__ dstA,
    const half_t* __restrict__ srcB, half_t* __restrict__ dstB,
    const half8 Bf[2][4][2], const float wih_v[2][4], const float bias_v[2][4],
    int l15, int quad, int jcol,
    float4v cstA[4], float4v cstB[4],
    const float* __restrict__ pW,          // full pW base (LAST only)
    float* __restrict__ wpw)               // wp[w] base: [64][2] floats (LAST only)
{
    float phA0, pcA0, phA1, pcA1, phB0, pcB0, phB1, pcB1;
    if (LAST) {
        // z = [h1(0:64), c1(64:128), h2(128:192), c2(192:256), hid(256:288)]
        phA0 = pW[jcol];             pcA0 = pW[64 + jcol];
        phA1 = pW[288 + jcol];       pcA1 = pW[288 + 64 + jcol];
        phB0 = pW[128 + jcol];       pcB0 = pW[128 + 64 + jcol];
        phB1 = pW[288 + 128 + jcol]; pcB1 = pW[288 + 128 + 64 + jcol];
    }
    #pragma unroll
    for (int mt = 0; mt < 4; ++mt) {
        // ---- MFMAs, layer A ----
        float4v x4A = *(const float4v*)&xtA[mt * 16 + quad * 4];
        half8 a0A = *(const half8*)&srcA[(mt * 16 + l15) * HROW + quad * 8];
        half8 a1A = *(const half8*)&srcA[(mt * 16 + l15) * HROW + 32 + quad * 8];
        float4v agA[4];
        #pragma unroll
        for (int gg = 0; gg < 4; ++gg) {
            float4v ai;
            #pragma unroll
            for (int reg = 0; reg < 4; ++reg) ai[reg] = fmaf(x4A[reg], wih_v[0][gg], bias_v[0][gg]);
            ai = __builtin_amdgcn_mfma_f32_16x16x32_f16(a0A, Bf[0][gg][0], ai, 0, 0, 0);
            ai = __builtin_amdgcn_mfma_f32_16x16x32_f16(a1A, Bf[0][gg][1], ai, 0, 0, 0);
            agA[gg] = ai;
        }
        // ---- MFMAs, layer B ----
        float4v x4B = *(const float4v*)&xtB[mt * 16 + quad * 4];
        half8 a0B = *(const half8*)&srcB[(mt * 16 + l15) * HROW + quad * 8];
        half8 a1B = *(const half8*)&srcB[(mt * 16 + l15) * HROW + 32 + quad * 8];
        float4v agB[4];
        #pragma unroll
        for (int gg = 0; gg < 4; ++gg) {
            float4v ai;
            #pragma unroll
            for (int reg = 0; reg < 4; ++reg) ai[reg] = fmaf(x4B[reg], wih_v[1][gg], bias_v[1][gg]);
            ai = __builtin_amdgcn_mfma_f32_16x16x32_f16(a0B, Bf[1][gg][0], ai, 0, 0, 0);
            ai = __builtin_amdgcn_mfma_f32_16x16x32_f16(a1B, Bf[1][gg][1], ai, 0, 0, 0);
            agB[gg] = ai;
        }

        float po0[4], po1[4];
        // ---- epilogue A (4 independent chains) ----
        #pragma unroll
        for (int reg = 0; reg < 4; ++reg) {
            float Bi  = ex2(agA[0][reg]);
            float Bff = ex2(agA[1][reg]);
            float Bg  = ex2(agA[2][reg]);
            float Bo  = ex2(agA[3][reg]);
            float ig  = fmaf(Bi, Bg, -Bi) * rcp_((1.0f + Bi) * (1.0f + Bg));
            float cn  = fmaf(Bff * rcp_(1.0f + Bff), cstA[mt][reg], ig);
            cstA[mt][reg] = cn;
            float Cc  = ex2(cn * L2E2);
            float hv  = fmaf(Bo, Cc, -Bo) * rcp_((1.0f + Bo) * (1.0f + Cc));
            if (LAST) {
                po0[reg] = fmaf(phA0, hv, pcA0 * cn);
                po1[reg] = fmaf(phA1, hv, pcA1 * cn);
            } else {
                dstA[(mt * 16 + quad * 4 + reg) * HROW + jcol] = (half_t)hv;
            }
        }
        // ---- epilogue B (4 more independent chains; compiler interleaves) ----
        #pragma unroll
        for (int reg = 0; reg < 4; ++reg) {
            float Bi  = ex2(agB[0][reg]);
            float Bff = ex2(agB[1][reg]);
            float Bg  = ex2(agB[2][reg]);
            float Bo  = ex2(agB[3][reg]);
            float ig  = fmaf(Bi, Bg, -Bi) * rcp_((1.0f + Bi) * (1.0f + Bg));
            float cn  = fmaf(Bff * rcp_(1.0f + Bff), cstB[mt][reg], ig);
            cstB[mt][reg] = cn;
            float Cc  = ex2(cn * L2E2);
            float hv  = fmaf(Bo, Cc, -Bo) * rcp_((1.0f + Bo) * (1.0f + Cc));
            if (LAST) {
                po0[reg] = fmaf(phB0, hv, fmaf(pcB0, cn, po0[reg]));
                po1[reg] = fmaf(phB1, hv, fmaf(pcB1, cn, po1[reg]));
            } else {
                dstB[(mt * 16 + quad * 4 + reg) * HROW + jcol] = (half_t)hv;
            }
        }
        if (LAST) {
            // single merged reduce over the 16 j-lanes sharing each batch row
            #pragma unroll
            for (int reg = 0; reg < 4; ++reg) {
                #pragma unroll
                for (int s = 1; s < 16; s <<= 1) {
                    po0[reg] += __shfl_xor(po0[reg], s, 64);
                    po1[reg] += __shfl_xor(po1[reg], s, 64);
                }
            }
            if (l15 == 0) {
                #pragma unroll
                for (int reg = 0; reg < 4; ++reg) {
                    int m = mt * 16 + quad * 4 + reg;
                    wpw[m * 2]     += po0[reg];
                    wpw[m * 2 + 1] += po1[reg];
                }
            }
        }
    }
    __syncthreads();
}

// launch_bounds(256,2): 256-reg combined budget. The interleaved kernel needs
// ~190-230 combined (both layers' Bf/cst live) -> fits without spills; (256,3)
// and (256,4) both spilled catastrophically (R1/R2: WRITE_SIZE 8MB -> 1.5-2GB).
// 2 blocks/CU is this structure's residency ceiling; we buy ILP, not waves.
extern "C" __global__ void __launch_bounds__(BLOCK, 2) lstm_mfma(
    const float* __restrict__ inputs,
    const float* __restrict__ Wih1, const float* __restrict__ Whh1,
    const float* __restrict__ bih1, const float* __restrict__ bhh1,
    const float* __restrict__ Wih2, const float* __restrict__ Whh2,
    const float* __restrict__ bih2, const float* __restrict__ bhh2,
    const float* __restrict__ pW,
    float* __restrict__ out, int n)
{
    __shared__ half_t hbufA[2 * 64 * HROW];  // 18 KB double-buffered h tile, layer 1
    __shared__ half_t hbufB[2 * 64 * HROW];  // 18 KB, layer 2
    __shared__ float  xt_lds[16 * 64];       // x transposed [t][b]
    __shared__ float  wp[4][64][2];          // per-wave projection partials

    const int tid  = threadIdx.x;
    const int w    = tid >> 6;
    const int lane = tid & 63;
    const int base = blockIdx.x * 64;
    const int l15  = lane & 15;
    const int quad = lane >> 4;
    const int jcol = w * 16 + l15;

    // zero wp (4*64*2 = 512 floats) and stage x transposed
    ((float2*)wp)[tid] = make_float2(0.0f, 0.0f);
    for (int idx = tid; idx < 64 * 18; idx += BLOCK) {
        int row = idx / 18, c = idx % 18;
        float v = inputs[(size_t)(base + row) * 18 + c];
        if (c < 16) xt_lds[c * 64 + row] = v;
    }
    __syncthreads();

    // ---- both layers' weight fragments, pre-scaled by log2e (g by 2*log2e) ----
    half8 Bf[2][4][2];
    float wih_v[2][4], bias_v[2][4];
    setup_weights(Wih1, Whh1, bih1, bhh1, quad, jcol, Bf[0], wih_v[0], bias_v[0]);
    setup_weights(Wih2, Whh2, bih2, bhh2, quad, jcol, Bf[1], wih_v[1], bias_v[1]);

    const float* xA = xt_lds;
    const float* xB = xt_lds + 8 * 64;

    float4v cstA[4], cstB[4];
    lstm_init(xA, wih_v[0], bias_v[0], hbufA, quad, jcol, cstA);
    lstm_init(xB, wih_v[1], bias_v[1], hbufB, quad, jcol, cstB);
    __syncthreads();

    float* wpw = &wp[w][0][0];
    half_t* A0 = hbufA; half_t* A1 = hbufA + 64 * HROW;
    half_t* B0 = hbufB; half_t* B1 = hbufB + 64 * HROW;

    // steps 1..6 as 3 double-buffered pairs, step 7 peeled with projection fold
    #pragma unroll 1
    for (int tt = 1; tt < 7; tt += 2) {
        lstm_step2<false>(xA + tt * 64,       xB + tt * 64,       A0, A1, B0, B1,
                          Bf, wih_v, bias_v, l15, quad, jcol, cstA, cstB, pW, wpw);
        lstm_step2<false>(xA + (tt + 1) * 64, xB + (tt + 1) * 64, A1, A0, B1, B0,
                          Bf, wih_v, bias_v, l15, quad, jcol, cstA, cstB, pW, wpw);
    }
    lstm_step2<true>(xA + 7 * 64, xB + 7 * 64, A0, A1, B0, B1,
                     Bf, wih_v, bias_v, l15, quad, jcol, cstA, cstB, pW, wpw);

    // final barrier already executed inside the last lstm_step2
    if (tid < 64) {
        int gb = base + tid;
        float2 o = ((float2*)out)[gb];   // MLP kernel ran first on this stream
        o.x += wp[0][tid][0] + wp[1][tid][0] + wp[2][tid][0] + wp[3][tid][0];
        o.y += wp[0][tid][1] + wp[1][tid][1] + wp[2][tid][1] + wp[3][tid][1];
        ((float2*)out)[gb] = o;
    }
}

extern "C" void kernel_launch(void* const* d_in, const int* in_sizes, int n_in,
                              void* d_out, int out_size, void* d_ws, size_t ws_size,
                              hipStream_t stream) {
    const int n = in_sizes[0] / 18;           // 1048576
    mlp_kernel<<<(n + BLOCK - 1) / BLOCK, BLOCK, 0, stream>>>(
        (const float*)d_in[0],
        (const float*)d_in[9],  (const float*)d_in[10],
        (const float*)d_in[11], (const float*)d_in[12],
        (const float*)d_in[13], (const float*)d_in[14],
        (const float*)d_in[15], (const float*)d_in[16],
        (float*)d_out, n);
    lstm_mfma<<<n / 64, BLOCK, 0, stream>>>(
        (const float*)d_in[0],
        (const float*)d_in[1], (const float*)d_in[2],
        (const float*)d_in[3], (const float*)d_in[4],
        (const float*)d_in[5], (const float*)d_in[6],
        (const float*)d_in[7], (const float*)d_in[8],
        (const float*)d_in[15],
        (float*)d_out, n);
}

// Round 4
// 2017.421 us; speedup vs baseline: 1.5139x; 1.5139x over previous
//
#include <hip/hip_runtime.h>

#define BLOCK 256
#define ROWS 128  // batch rows per block: 8 mt-subtiles/wave -> 2x independent trans chains
                  // per step (ILP for the latency-bound epilogue) sharing ONE set of weight
                  // regs, and half the barrier events per element vs ROWS=64.
#define MT   (ROWS / 16)
#define HROW 72   // LDS h-tile row stride in halves (144 B): 36 words ≡ 4 mod 32 -> 2-way (free) on b128 reads

typedef _Float16 half_t;
typedef __attribute__((ext_vector_type(8))) _Float16 half8;
typedef __attribute__((ext_vector_type(4))) float float4v;

#define L2E  1.4426950408889634f
#define L2E2 2.8853900817779268f

__device__ __forceinline__ float rcp_(float x) { return __builtin_amdgcn_rcpf(x); }
__device__ __forceinline__ float ex2(float x)  { return __builtin_amdgcn_exp2f(x); }

// ---------------- MLP kernel (near its 157TF vector roofline; untouched) ----------------
extern "C" __global__ void __launch_bounds__(BLOCK, 1) mlp_kernel(
    const float* __restrict__ inputs,
    const float* __restrict__ mW0, const float* __restrict__ mb0,
    const float* __restrict__ mW1, const float* __restrict__ mb1,
    const float* __restrict__ mW2, const float* __restrict__ mb2,
    const float* __restrict__ pW, const float* __restrict__ pb,
    float* __restrict__ out, int n)
{
    int b = blockIdx.x * BLOCK + threadIdx.x;
    if (b >= n) return;
    float f0 = inputs[(size_t)b * 18 + 16], f1 = inputs[(size_t)b * 18 + 17];
    float h0[64];
    #pragma unroll
    for (int i = 0; i < 64; ++i)
        h0[i] = fmaxf(fmaf(mW0[2 * i], f0, fmaf(mW0[2 * i + 1], f1, mb0[i])), 0.0f);
    float acc2[32];
    #pragma unroll
    for (int j = 0; j < 32; ++j) acc2[j] = mb2[j];
    #pragma unroll 2
    for (int i = 0; i < 64; ++i) {
        float a = mb1[i];
        #pragma unroll
        for (int k = 0; k < 64; ++k) a = fmaf(mW1[i * 64 + k], h0[k], a);
        a = fmaxf(a, 0.0f);
        #pragma unroll
        for (int j = 0; j < 32; ++j) acc2[j] = fmaf(mW2[j * 64 + i], a, acc2[j]);
    }
    float out0 = pb[0], out1 = pb[1];
    #pragma unroll
    for (int j = 0; j < 32; ++j) {
        out0 = fmaf(pW[256 + j], acc2[j], out0);
        out1 = fmaf(pW[288 + 256 + j], acc2[j], out1);
    }
    ((float2*)out)[b] = make_float2(out0, out1);
}

// ---------------- LSTM step ----------------
// Per-mt processing: 8 MFMAs + epilogue per batch-subtile; MT=8 subtiles give the
// scheduler 8 independent trans chains between barriers. LAST folds the projection
// and butterfly-reduces it into LDS wp immediately -> no persistent po registers.
template <bool LAST>
__device__ __forceinline__ void lstm_step(
    const float* __restrict__ xt,          // xt + t*ROWS
    const half_t* __restrict__ src, half_t* __restrict__ dst,
    const half8 Bf[4][2], const float wih_v[4], const float bias_v[4],
    int l15, int quad, int jcol,
    float4v cst[MT],
    const float* __restrict__ pWz,         // pW + zbase (LAST only)
    float* __restrict__ wpw)               // wp[w] base: [ROWS][2] floats (LAST only)
{
    float ph0, pc0, ph1, pc1;
    if (LAST) {
        ph0 = pWz[jcol];       pc0 = pWz[64 + jcol];
        ph1 = pWz[288 + jcol]; pc1 = pWz[288 + 64 + jcol];
    }
    #pragma unroll
    for (int mt = 0; mt < MT; ++mt) {
        float4v x4 = *(const float4v*)&xt[mt * 16 + quad * 4];
        half8 a0 = *(const half8*)&src[(mt * 16 + l15) * HROW + quad * 8];
        half8 a1 = *(const half8*)&src[(mt * 16 + l15) * HROW + 32 + quad * 8];
        float4v ag[4];
        #pragma unroll
        for (int gg = 0; gg < 4; ++gg) {
            float4v ai;
            #pragma unroll
            for (int reg = 0; reg < 4; ++reg) ai[reg] = fmaf(x4[reg], wih_v[gg], bias_v[gg]);
            ai = __builtin_amdgcn_mfma_f32_16x16x32_f16(a0, Bf[gg][0], ai, 0, 0, 0);
            ai = __builtin_amdgcn_mfma_f32_16x16x32_f16(a1, Bf[gg][1], ai, 0, 0, 0);
            ag[gg] = ai;
        }
        float po0[4], po1[4];
        #pragma unroll
        for (int reg = 0; reg < 4; ++reg) {
            float Bi  = ex2(ag[0][reg]);
            float Bff = ex2(ag[1][reg]);
            float Bg  = ex2(ag[2][reg]);
            float Bo  = ex2(ag[3][reg]);
            float ig  = fmaf(Bi, Bg, -Bi) * rcp_((1.0f + Bi) * (1.0f + Bg));
            float cn  = fmaf(Bff * rcp_(1.0f + Bff), cst[mt][reg], ig);
            cst[mt][reg] = cn;
            float Cc  = ex2(cn * L2E2);
            float hv  = fmaf(Bo, Cc, -Bo) * rcp_((1.0f + Bo) * (1.0f + Cc));
            if (LAST) {
                po0[reg] = fmaf(ph0, hv, pc0 * cn);
                po1[reg] = fmaf(ph1, hv, pc1 * cn);
            } else {
                dst[(mt * 16 + quad * 4 + reg) * HROW + jcol] = (half_t)hv;
            }
        }
        if (LAST) {
            // reduce over the 16 j-lanes sharing each batch row, accumulate into wp
            #pragma unroll
            for (int reg = 0; reg < 4; ++reg) {
                #pragma unroll
                for (int s = 1; s < 16; s <<= 1) {
                    po0[reg] += __shfl_xor(po0[reg], s, 64);
                    po1[reg] += __shfl_xor(po1[reg], s, 64);
                }
            }
            if (l15 == 0) {
                #pragma unroll
                for (int reg = 0; reg < 4; ++reg) {
                    int m = mt * 16 + quad * 4 + reg;
                    wpw[m * 2]     += po0[reg];
                    wpw[m * 2 + 1] += po1[reg];
                }
            }
        }
    }
    __syncthreads();
}

__device__ __forceinline__ void lstm_mfma_one(
    const float* __restrict__ Wih, const float* __restrict__ Whh,
    const float* __restrict__ bih, const float* __restrict__ bhh,
    const float* __restrict__ pW, int zbase,
    const float* __restrict__ xt,            // xt[t*ROWS + b], t in 0..7
    half_t* __restrict__ hbuf,               // [2][ROWS*HROW]
    int w, int lane,
    float* __restrict__ wpw)                 // wp[w] base
{
    const int l15  = lane & 15;
    const int quad = lane >> 4;
    const int jcol = w * 16 + l15;

    // --- weight fragments, PRE-SCALED by log2e (g-gate by 2*log2e) ---
    const float gscale[4] = {L2E, L2E, L2E2, L2E};
    half8 Bf[4][2];
    float wih_v[4], bias_v[4];
    #pragma unroll
    for (int gg = 0; gg < 4; ++gg) {
        const int nrow = gg * 64 + jcol;
        const float s = gscale[gg];
        #pragma unroll
        for (int kf = 0; kf < 2; ++kf) {
            const float4* p = (const float4*)(Whh + nrow * 64 + kf * 32 + quad * 8);
            float4 w0 = p[0], w1 = p[1];
            Bf[gg][kf] = half8{(half_t)(w0.x * s), (half_t)(w0.y * s), (half_t)(w0.z * s), (half_t)(w0.w * s),
                               (half_t)(w1.x * s), (half_t)(w1.y * s), (half_t)(w1.z * s), (half_t)(w1.w * s)};
        }
        wih_v[gg]  = Wih[nrow] * s;
        bias_v[gg] = (bih[nrow] + bhh[nrow]) * s;
    }

    float4v cst[MT];

    // --- t = 0: h = c = 0 -> preacts = x*wih_s + b_s (already log2e-scaled) ---
    #pragma unroll
    for (int mt = 0; mt < MT; ++mt) {
        float4v x4 = *(const float4v*)&xt[mt * 16 + quad * 4];
        #pragma unroll
        for (int reg = 0; reg < 4; ++reg) {
            float Bi = ex2(fmaf(x4[reg], wih_v[0], bias_v[0]));
            float Bg = ex2(fmaf(x4[reg], wih_v[2], bias_v[2]));
            float Bo = ex2(fmaf(x4[reg], wih_v[3], bias_v[3]));
            float cn = fmaf(Bi, Bg, -Bi) * rcp_((1.0f + Bi) * (1.0f + Bg));
            cst[mt][reg] = cn;
            float Cc = ex2(cn * L2E2);
            float hv = fmaf(Bo, Cc, -Bo) * rcp_((1.0f + Bo) * (1.0f + Cc));
            hbuf[(mt * 16 + quad * 4 + reg) * HROW + jcol] = (half_t)hv;  // buf 0
        }
    }
    __syncthreads();

    half_t* b0 = hbuf;
    half_t* b1 = hbuf + ROWS * HROW;
    // steps 1..6 as 3 double-buffered pairs, step 7 peeled with projection fold
    #pragma unroll 1
    for (int tt = 1; tt < 7; tt += 2) {
        lstm_step<false>(xt + tt * ROWS,       b0, b1, Bf, wih_v, bias_v, l15, quad, jcol,
                         cst, pW, wpw);
        lstm_step<false>(xt + (tt + 1) * ROWS, b1, b0, Bf, wih_v, bias_v, l15, quad, jcol,
                         cst, pW, wpw);
    }
    lstm_step<true>(xt + 7 * ROWS, b0, b1, Bf, wih_v, bias_v, l15, quad, jcol,
                    cst, pW + zbase, wpw);
}

// launch_bounds(256,2): 256-reg combined budget — the ONLY no-spill bracket for
// this structure (R1: (256,4) -> 2.1GB spill; R2: (256,3) -> 1.6GB spill; R3:
// 2-layer interleave at (256,2) -> 2.7GB spill). ROWS=128 adds only cst[8]
// (+16 f32) over the proven ROWS=64 allocation -> stays inside 256.
extern "C" __global__ void __launch_bounds__(BLOCK, 2) lstm_mfma(
    const float* __restrict__ inputs,
    const float* __restrict__ Wih1, const float* __restrict__ Whh1,
    const float* __restrict__ bih1, const float* __restrict__ bhh1,
    const float* __restrict__ Wih2, const float* __restrict__ Whh2,
    const float* __restrict__ bih2, const float* __restrict__ bhh2,
    const float* __restrict__ pW,
    float* __restrict__ out, int n)
{
    __shared__ half_t hbuf[2 * ROWS * HROW]; // 36 KB double-buffered h tile
    __shared__ float  xt_lds[16 * ROWS];     // x transposed [t][b]   (8 KB)
    __shared__ float  wp[4][ROWS][2];        // per-wave projection partials (4 KB)

    const int tid  = threadIdx.x;
    const int w    = tid >> 6;
    const int lane = tid & 63;
    const int base = blockIdx.x * ROWS;

    // zero wp (4*128*2 = 1024 floats) and stage x transposed
    ((float4*)wp)[tid] = make_float4(0.0f, 0.0f, 0.0f, 0.0f);
    for (int idx = tid; idx < ROWS * 18; idx += BLOCK) {
        int row = idx / 18, c = idx % 18;
        float v = inputs[(size_t)(base + row) * 18 + c];
        if (c < 16) xt_lds[c * ROWS + row] = v;
    }
    __syncthreads();

    float* wpw = &wp[w][0][0];
    lstm_mfma_one(Wih1, Whh1, bih1, bhh1, pW, 0,   xt_lds,            hbuf, w, lane, wpw);
    lstm_mfma_one(Wih2, Whh2, bih2, bhh2, pW, 128, xt_lds + 8 * ROWS, hbuf, w, lane, wpw);

    // final barrier already executed inside the last lstm_step
    if (tid < ROWS) {
        int gb = base + tid;
        float2 o = ((float2*)out)[gb];   // MLP kernel ran first on this stream
        o.x += wp[0][tid][0] + wp[1][tid][0] + wp[2][tid][0] + wp[3][tid][0];
        o.y += wp[0][tid][1] + wp[1][tid][1] + wp[2][tid][1] + wp[3][tid][1];
        ((float2*)out)[gb] = o;
    }
}

extern "C" void kernel_launch(void* const* d_in, const int* in_sizes, int n_in,
                              void* d_out, int out_size, void* d_ws, size_t ws_size,
                              hipStream_t stream) {
    const int n = in_sizes[0] / 18;           // 1048576
    mlp_kernel<<<(n + BLOCK - 1) / BLOCK, BLOCK, 0, stream>>>(
        (const float*)d_in[0],
        (const float*)d_in[9],  (const float*)d_in[10],
        (const float*)d_in[11], (const float*)d_in[12],
        (const float*)d_in[13], (const float*)d_in[14],
        (const float*)d_in[15], (const float*)d_in[16],
        (float*)d_out, n);
    lstm_mfma<<<n / ROWS, BLOCK, 0, stream>>>(
        (const float*)d_in[0],
        (const float*)d_in[1], (const float*)d_in[2],
        (const float*)d_in[3], (const float*)d_in[4],
        (const float*)d_in[5], (const float*)d_in[6],
        (const float*)d_in[7], (const float*)d_in[8],
        (const float*)d_in[15],
        (float*)d_out, n);
}

// Round 7
// 1689.355 us; speedup vs baseline: 1.8079x; 1.1942x over previous
//
#include <hip/hip_runtime.h>

#define BLOCK 256
#define HROW 72   // LDS h-tile row stride in halves (144 B): 36 words ≡ 4 mod 32 -> 2-way (free) on b128 reads

typedef _Float16 half_t;
typedef __attribute__((ext_vector_type(8))) _Float16 half8;
typedef __attribute__((ext_vector_type(4))) float float4v;

#define L2E  1.4426950408889634f
#define L2E2 2.8853900817779268f

__device__ __forceinline__ float rcp_(float x) { return __builtin_amdgcn_rcpf(x); }
__device__ __forceinline__ float ex2(float x)  { return __builtin_amdgcn_exp2f(x); }

// Zero the output so both fused paths can accumulate with atomicAdd (exactly
// two adds per element). Mechanism correctness-validated in R1 (passed,
// absmax 0.001953125). Self-contained per launch -> replay-safe.
extern "C" __global__ void zero_out(float2* __restrict__ out, int n) {
    int i = blockIdx.x * BLOCK + threadIdx.x;
    if (i < n) out[i] = make_float2(0.0f, 0.0f);
}

// ---------------- LSTM step (R0 arithmetic, UNTOUCHED — knife-edge absmax) ----------------
// R5/R6 lesson: merged-rcp AND f32x2 packing both broke absmax (5.9e-2/3.05e-2).
// Only the exact scalar op sequence below is certified.
template <bool LAST>
__device__ __forceinline__ void lstm_step(
    const float* __restrict__ xt,          // xt + t*64
    const half_t* __restrict__ src, half_t* __restrict__ dst,
    const half8 Bf[4][2], const float wih_v[4], const float bias_v[4],
    int l15, int quad, int jcol,
    float4v cst[4],
    const float* __restrict__ pWz,         // pW + zbase (LAST only)
    float* __restrict__ wpw)               // wp[w] base: [64][2] floats (LAST only)
{
    float ph0, pc0, ph1, pc1;
    if (LAST) {
        ph0 = pWz[jcol];       pc0 = pWz[64 + jcol];
        ph1 = pWz[288 + jcol]; pc1 = pWz[288 + 64 + jcol];
    }
    #pragma unroll
    for (int mt = 0; mt < 4; ++mt) {
        float4v x4 = *(const float4v*)&xt[mt * 16 + quad * 4];
        half8 a0 = *(const half8*)&src[(mt * 16 + l15) * HROW + quad * 8];
        half8 a1 = *(const half8*)&src[(mt * 16 + l15) * HROW + 32 + quad * 8];
        float4v ag[4];
        #pragma unroll
        for (int gg = 0; gg < 4; ++gg) {
            float4v ai;
            #pragma unroll
            for (int reg = 0; reg < 4; ++reg) ai[reg] = fmaf(x4[reg], wih_v[gg], bias_v[gg]);
            ai = __builtin_amdgcn_mfma_f32_16x16x32_f16(a0, Bf[gg][0], ai, 0, 0, 0);
            ai = __builtin_amdgcn_mfma_f32_16x16x32_f16(a1, Bf[gg][1], ai, 0, 0, 0);
            ag[gg] = ai;
        }
        float po0[4], po1[4];
        #pragma unroll
        for (int reg = 0; reg < 4; ++reg) {
            float Bi  = ex2(ag[0][reg]);
            float Bff = ex2(ag[1][reg]);
            float Bg  = ex2(ag[2][reg]);
            float Bo  = ex2(ag[3][reg]);
            float ig  = fmaf(Bi, Bg, -Bi) * rcp_((1.0f + Bi) * (1.0f + Bg));
            float cn  = fmaf(Bff * rcp_(1.0f + Bff), cst[mt][reg], ig);
            cst[mt][reg] = cn;
            float Cc  = ex2(cn * L2E2);
            float hv  = fmaf(Bo, Cc, -Bo) * rcp_((1.0f + Bo) * (1.0f + Cc));
            if (LAST) {
                po0[reg] = fmaf(ph0, hv, pc0 * cn);
                po1[reg] = fmaf(ph1, hv, pc1 * cn);
            } else {
                dst[(mt * 16 + quad * 4 + reg) * HROW + jcol] = (half_t)hv;
            }
        }
        if (LAST) {
            // reduce over the 16 j-lanes sharing each batch row, accumulate into wp
            #pragma unroll
            for (int reg = 0; reg < 4; ++reg) {
                #pragma unroll
                for (int s = 1; s < 16; s <<= 1) {
                    po0[reg] += __shfl_xor(po0[reg], s, 64);
                    po1[reg] += __shfl_xor(po1[reg], s, 64);
                }
            }
            if (l15 == 0) {
                #pragma unroll
                for (int reg = 0; reg < 4; ++reg) {
                    int m = mt * 16 + quad * 4 + reg;
                    wpw[m * 2]     += po0[reg];
                    wpw[m * 2 + 1] += po1[reg];
                }
            }
        }
    }
    __syncthreads();
}

__device__ __forceinline__ void lstm_mfma_one(
    const float* __restrict__ Wih, const float* __restrict__ Whh,
    const float* __restrict__ bih, const float* __restrict__ bhh,
    const float* __restrict__ pW, int zbase,
    const float* __restrict__ xt,            // xt[t*64 + b], t in 0..7
    half_t* __restrict__ hbuf,               // [2][64*HROW]
    int w, int lane,
    float* __restrict__ wpw)                 // wp[w] base
{
    const int l15  = lane & 15;
    const int quad = lane >> 4;
    const int jcol = w * 16 + l15;

    // --- weight fragments, PRE-SCALED by log2e (g-gate by 2*log2e) ---
    const float gscale[4] = {L2E, L2E, L2E2, L2E};
    half8 Bf[4][2];
    float wih_v[4], bias_v[4];
    #pragma unroll
    for (int gg = 0; gg < 4; ++gg) {
        const int nrow = gg * 64 + jcol;
        const float s = gscale[gg];
        #pragma unroll
        for (int kf = 0; kf < 2; ++kf) {
            const float4* p = (const float4*)(Whh + nrow * 64 + kf * 32 + quad * 8);
            float4 w0 = p[0], w1 = p[1];
            Bf[gg][kf] = half8{(half_t)(w0.x * s), (half_t)(w0.y * s), (half_t)(w0.z * s), (half_t)(w0.w * s),
                               (half_t)(w1.x * s), (half_t)(w1.y * s), (half_t)(w1.z * s), (half_t)(w1.w * s)};
        }
        wih_v[gg]  = Wih[nrow] * s;
        bias_v[gg] = (bih[nrow] + bhh[nrow]) * s;
    }

    float4v cst[4];

    // --- t = 0: h = c = 0 -> preacts = x*wih_s + b_s (already log2e-scaled) ---
    #pragma unroll
    for (int mt = 0; mt < 4; ++mt) {
        float4v x4 = *(const float4v*)&xt[mt * 16 + quad * 4];
        #pragma unroll
        for (int reg = 0; reg < 4; ++reg) {
            float Bi = ex2(fmaf(x4[reg], wih_v[0], bias_v[0]));
            float Bg = ex2(fmaf(x4[reg], wih_v[2], bias_v[2]));
            float Bo = ex2(fmaf(x4[reg], wih_v[3], bias_v[3]));
            float cn = fmaf(Bi, Bg, -Bi) * rcp_((1.0f + Bi) * (1.0f + Bg));
            cst[mt][reg] = cn;
            float Cc = ex2(cn * L2E2);
            float hv = fmaf(Bo, Cc, -Bo) * rcp_((1.0f + Bo) * (1.0f + Cc));
            hbuf[(mt * 16 + quad * 4 + reg) * HROW + jcol] = (half_t)hv;  // buf 0
        }
    }
    __syncthreads();

    half_t* b0 = hbuf;
    half_t* b1 = hbuf + 64 * HROW;
    // steps 1..6 as 3 double-buffered pairs, step 7 peeled with projection fold
    #pragma unroll 1
    for (int tt = 1; tt < 7; tt += 2) {
        lstm_step<false>(xt + tt * 64,       b0, b1, Bf, wih_v, bias_v, l15, quad, jcol,
                         cst, pW, wpw);
        lstm_step<false>(xt + (tt + 1) * 64, b1, b0, Bf, wih_v, bias_v, l15, quad, jcol,
                         cst, pW, wpw);
    }
    lstm_step<true>(xt + 7 * 64, b0, b1, Bf, wih_v, bias_v, l15, quad, jcol,
                    cst, pW + zbase, wpw);
}

// ---------------- fused kernel ----------------
// Every 5th block runs the (barrier-free, pure-VALU) MLP path; 4/5 run the
// R0 LSTM path (ROWS=64). The MLP's ~112us of serial work gets absorbed into
// the LSTM's idle issue slots. launch_bounds(256,2): the ONLY no-spill bracket
// (R1 (256,4), R2 (256,3), R3 2-layer, R4 ROWS=128 all spilled 1.5-2.7GB).
// MLP path register need (~110) < LSTM path (~230) -> allocation matches R0.
extern "C" __global__ void __launch_bounds__(BLOCK, 2) lstm_mfma(
    const float* __restrict__ inputs,
    const float* __restrict__ Wih1, const float* __restrict__ Whh1,
    const float* __restrict__ bih1, const float* __restrict__ bhh1,
    const float* __restrict__ Wih2, const float* __restrict__ Whh2,
    const float* __restrict__ bih2, const float* __restrict__ bhh2,
    const float* __restrict__ mW0, const float* __restrict__ mb0,
    const float* __restrict__ mW1, const float* __restrict__ mb1,
    const float* __restrict__ mW2, const float* __restrict__ mb2,
    const float* __restrict__ pW, const float* __restrict__ pb,
    float* __restrict__ out, int n)
{
    __shared__ half_t hbuf[2 * 64 * HROW];   // 18 KB double-buffered h tile
    __shared__ float  xt_lds[16 * 64];       // x transposed [t][b]
    __shared__ float  wp[4][64][2];          // per-wave projection partials (accumulated)

    const int g = blockIdx.x / 5;
    const int r = blockIdx.x % 5;
    const int tid = threadIdx.x;

    if (r == 4) {
        // ---------------- MLP path (R0 mlp_kernel body, atomic accumulate) ----------------
        int b = g * BLOCK + tid;
        if (b < n) {
            float f0 = inputs[(size_t)b * 18 + 16], f1 = inputs[(size_t)b * 18 + 17];
            float h0[64];
            #pragma unroll
            for (int i = 0; i < 64; ++i)
                h0[i] = fmaxf(fmaf(mW0[2 * i], f0, fmaf(mW0[2 * i + 1], f1, mb0[i])), 0.0f);
            float acc2[32];
            #pragma unroll
            for (int j = 0; j < 32; ++j) acc2[j] = mb2[j];
            #pragma unroll 2
            for (int i = 0; i < 64; ++i) {
                float a = mb1[i];
                #pragma unroll
                for (int k = 0; k < 64; ++k) a = fmaf(mW1[i * 64 + k], h0[k], a);
                a = fmaxf(a, 0.0f);
                #pragma unroll
                for (int j = 0; j < 32; ++j) acc2[j] = fmaf(mW2[j * 64 + i], a, acc2[j]);
            }
            float out0 = pb[0], out1 = pb[1];
            #pragma unroll
            for (int j = 0; j < 32; ++j) {
                out0 = fmaf(pW[256 + j], acc2[j], out0);
                out1 = fmaf(pW[288 + 256 + j], acc2[j], out1);
            }
            atomicAdd(&out[2 * (size_t)b],     out0);
            atomicAdd(&out[2 * (size_t)b + 1], out1);
        }
        return;
    }

    // ---------------- LSTM path (R0 body, ROWS=64) ----------------
    const int lb   = g * 4 + r;              // lstm block id, [0, n/64)
    const int w    = tid >> 6;
    const int lane = tid & 63;
    const int base = lb * 64;

    // zero wp (4*64*2 = 512 floats) and stage x transposed
    ((float2*)wp)[tid] = make_float2(0.0f, 0.0f);
    for (int idx = tid; idx < 64 * 18; idx += BLOCK) {
        int row = idx / 18, c = idx % 18;
        float v = inputs[(size_t)(base + row) * 18 + c];
        if (c < 16) xt_lds[c * 64 + row] = v;
    }
    __syncthreads();

    float* wpw = &wp[w][0][0];
    lstm_mfma_one(Wih1, Whh1, bih1, bhh1, pW, 0,   xt_lds,          hbuf, w, lane, wpw);
    lstm_mfma_one(Wih2, Whh2, bih2, bhh2, pW, 128, xt_lds + 8 * 64, hbuf, w, lane, wpw);

    // final barrier already executed inside the last lstm_step
    if (tid < 64) {
        int gb = base + tid;
        float sx = wp[0][tid][0] + wp[1][tid][0] + wp[2][tid][0] + wp[3][tid][0];
        float sy = wp[0][tid][1] + wp[1][tid][1] + wp[2][tid][1] + wp[3][tid][1];
        atomicAdd(&out[2 * (size_t)gb],     sx);
        atomicAdd(&out[2 * (size_t)gb + 1], sy);
    }
}

extern "C" void kernel_launch(void* const* d_in, const int* in_sizes, int n_in,
                              void* d_out, int out_size, void* d_ws, size_t ws_size,
                              hipStream_t stream) {
    const int n = in_sizes[0] / 18;           // 1048576
    const int nmlp = (n + BLOCK - 1) / BLOCK; // 4096 MLP blocks
    const int ngrid = nmlp * 5;               // 20480 = 16384 lstm + 4096 mlp

    zero_out<<<nmlp, BLOCK, 0, stream>>>((float2*)d_out, n);
    lstm_mfma<<<ngrid, BLOCK, 0, stream>>>(
        (const float*)d_in[0],
        (const float*)d_in[1],  (const float*)d_in[2],
        (const float*)d_in[3],  (const float*)d_in[4],
        (const float*)d_in[5],  (const float*)d_in[6],
        (const float*)d_in[7],  (const float*)d_in[8],
        (const float*)d_in[9],  (const float*)d_in[10],
        (const float*)d_in[11], (const float*)d_in[12],
        (const float*)d_in[13], (const float*)d_in[14],
        (const float*)d_in[15], (const float*)d_in[16],
        (float*)d_out, n);
}

// Round 8
// 1533.600 us; speedup vs baseline: 1.9915x; 1.1016x over previous
//
#include <hip/hip_runtime.h>

#define BLOCK 256
#define HROW 72   // LDS h-tile row stride in halves (144 B): 36 words ≡ 4 mod 32 -> 2-way (free) on b128 reads

typedef _Float16 half_t;
typedef __attribute__((ext_vector_type(8))) _Float16 half8;
typedef __attribute__((ext_vector_type(4))) float float4v;

#define L2E  1.4426950408889634f
#define L2E2 2.8853900817779268f

__device__ __forceinline__ float rcp_(float x) { return __builtin_amdgcn_rcpf(x); }
__device__ __forceinline__ float ex2(float x)  { return __builtin_amdgcn_exp2f(x); }

// ---------------- MLP kernel (near its 157TF vector roofline; untouched) ----------------
extern "C" __global__ void __launch_bounds__(BLOCK, 1) mlp_kernel(
    const float* __restrict__ inputs,
    const float* __restrict__ mW0, const float* __restrict__ mb0,
    const float* __restrict__ mW1, const float* __restrict__ mb1,
    const float* __restrict__ mW2, const float* __restrict__ mb2,
    const float* __restrict__ pW, const float* __restrict__ pb,
    float* __restrict__ out, int n)
{
    int b = blockIdx.x * BLOCK + threadIdx.x;
    if (b >= n) return;
    float f0 = inputs[(size_t)b * 18 + 16], f1 = inputs[(size_t)b * 18 + 17];
    float h0[64];
    #pragma unroll
    for (int i = 0; i < 64; ++i)
        h0[i] = fmaxf(fmaf(mW0[2 * i], f0, fmaf(mW0[2 * i + 1], f1, mb0[i])), 0.0f);
    float acc2[32];
    #pragma unroll
    for (int j = 0; j < 32; ++j) acc2[j] = mb2[j];
    #pragma unroll 2
    for (int i = 0; i < 64; ++i) {
        float a = mb1[i];
        #pragma unroll
        for (int k = 0; k < 64; ++k) a = fmaf(mW1[i * 64 + k], h0[k], a);
        a = fmaxf(a, 0.0f);
        #pragma unroll
        for (int j = 0; j < 32; ++j) acc2[j] = fmaf(mW2[j * 64 + i], a, acc2[j]);
    }
    float out0 = pb[0], out1 = pb[1];
    #pragma unroll
    for (int j = 0; j < 32; ++j) {
        out0 = fmaf(pW[256 + j], acc2[j], out0);
        out1 = fmaf(pW[288 + 256 + j], acc2[j], out1);
    }
    ((float2*)out)[b] = make_float2(out0, out1);
}

// ---------------- LSTM step (R0 arithmetic EXACTLY — knife-edge absmax) ----------------
// R5/R6 lesson: merged-rcp AND f32x2 packing both broke absmax. Only this
// scalar op sequence is certified. New here: the 4-subtile loop is split into
// two 2-subtile groups fenced by sched_barrier(0), pinning the scheduler's
// live-range window to ~half (R1/R2 spilled because the unconstrained 4-mt
// window needs ~200+ regs). With the smaller window the kernel targets the
// (256,3) budget (~170 regs) -> 3 blocks/CU.
template <bool LAST>
__device__ __forceinline__ void lstm_step(
    const float* __restrict__ xt,          // xt + t*64
    const half_t* __restrict__ src, half_t* __restrict__ dst,
    const half8 Bf[4][2], const float wih_v[4], const float bias_v[4],
    int l15, int quad, int jcol,
    float4v cst[4],
    const float* __restrict__ pWz,         // pW + zbase (LAST only)
    float* __restrict__ wpw)               // wp[w] base: [64][2] floats (LAST only)
{
    float ph0, pc0, ph1, pc1;
    if (LAST) {
        ph0 = pWz[jcol];       pc0 = pWz[64 + jcol];
        ph1 = pWz[288 + jcol]; pc1 = pWz[288 + 64 + jcol];
    }
    // mt_ must be a LITERAL so cst[] stays statically indexed (no scratch).
    #define LSTM_MT(mt_)                                                          \
    {                                                                             \
        float4v x4 = *(const float4v*)&xt[(mt_) * 16 + quad * 4];                 \
        half8 a0 = *(const half8*)&src[((mt_) * 16 + l15) * HROW + quad * 8];     \
        half8 a1 = *(const half8*)&src[((mt_) * 16 + l15) * HROW + 32 + quad * 8];\
        float4v ag[4];                                                            \
        _Pragma("unroll")                                                         \
        for (int gg = 0; gg < 4; ++gg) {                                          \
            float4v ai;                                                           \
            _Pragma("unroll")                                                     \
            for (int reg = 0; reg < 4; ++reg)                                     \
                ai[reg] = fmaf(x4[reg], wih_v[gg], bias_v[gg]);                   \
            ai = __builtin_amdgcn_mfma_f32_16x16x32_f16(a0, Bf[gg][0], ai, 0, 0, 0);\
            ai = __builtin_amdgcn_mfma_f32_16x16x32_f16(a1, Bf[gg][1], ai, 0, 0, 0);\
            ag[gg] = ai;                                                          \
        }                                                                         \
        float po0[4], po1[4];                                                     \
        _Pragma("unroll")                                                         \
        for (int reg = 0; reg < 4; ++reg) {                                       \
            float Bi  = ex2(ag[0][reg]);                                          \
            float Bff = ex2(ag[1][reg]);                                          \
            float Bg  = ex2(ag[2][reg]);                                          \
            float Bo  = ex2(ag[3][reg]);                                          \
            float ig  = fmaf(Bi, Bg, -Bi) * rcp_((1.0f + Bi) * (1.0f + Bg));      \
            float cn  = fmaf(Bff * rcp_(1.0f + Bff), cst[mt_][reg], ig);          \
            cst[mt_][reg] = cn;                                                   \
            float Cc  = ex2(cn * L2E2);                                           \
            float hv  = fmaf(Bo, Cc, -Bo) * rcp_((1.0f + Bo) * (1.0f + Cc));      \
            if (LAST) {                                                           \
                po0[reg] = fmaf(ph0, hv, pc0 * cn);                               \
                po1[reg] = fmaf(ph1, hv, pc1 * cn);                               \
            } else {                                                              \
                dst[((mt_) * 16 + quad * 4 + reg) * HROW + jcol] = (half_t)hv;    \
            }                                                                     \
        }                                                                         \
        if (LAST) {                                                               \
            _Pragma("unroll")                                                     \
            for (int reg = 0; reg < 4; ++reg) {                                   \
                _Pragma("unroll")                                                 \
                for (int s = 1; s < 16; s <<= 1) {                                \
                    po0[reg] += __shfl_xor(po0[reg], s, 64);                      \
                    po1[reg] += __shfl_xor(po1[reg], s, 64);                      \
                }                                                                 \
            }                                                                     \
            if (l15 == 0) {                                                       \
                _Pragma("unroll")                                                 \
                for (int reg = 0; reg < 4; ++reg) {                               \
                    int m = (mt_) * 16 + quad * 4 + reg;                          \
                    wpw[m * 2]     += po0[reg];                                   \
                    wpw[m * 2 + 1] += po1[reg];                                   \
                }                                                                 \
            }                                                                     \
        }                                                                         \
    }

    LSTM_MT(0)
    LSTM_MT(1)
    __builtin_amdgcn_sched_barrier(0);   // cap live-range window at 2 subtiles
    LSTM_MT(2)
    LSTM_MT(3)
    #undef LSTM_MT

    __syncthreads();
}

__device__ __forceinline__ void lstm_mfma_one(
    const float* __restrict__ Wih, const float* __restrict__ Whh,
    const float* __restrict__ bih, const float* __restrict__ bhh,
    const float* __restrict__ pW, int zbase,
    const float* __restrict__ xt,            // xt[t*64 + b], t in 0..7
    half_t* __restrict__ hbuf,               // [2][64*HROW]
    int w, int lane,
    float* __restrict__ wpw)                 // wp[w] base
{
    const int l15  = lane & 15;
    const int quad = lane >> 4;
    const int jcol = w * 16 + l15;

    // --- weight fragments, PRE-SCALED by log2e (g-gate by 2*log2e) ---
    const float gscale[4] = {L2E, L2E, L2E2, L2E};
    half8 Bf[4][2];
    float wih_v[4], bias_v[4];
    #pragma unroll
    for (int gg = 0; gg < 4; ++gg) {
        const int nrow = gg * 64 + jcol;
        const float s = gscale[gg];
        #pragma unroll
        for (int kf = 0; kf < 2; ++kf) {
            const float4* p = (const float4*)(Whh + nrow * 64 + kf * 32 + quad * 8);
            float4 w0 = p[0], w1 = p[1];
            Bf[gg][kf] = half8{(half_t)(w0.x * s), (half_t)(w0.y * s), (half_t)(w0.z * s), (half_t)(w0.w * s),
                               (half_t)(w1.x * s), (half_t)(w1.y * s), (half_t)(w1.z * s), (half_t)(w1.w * s)};
        }
        wih_v[gg]  = Wih[nrow] * s;
        bias_v[gg] = (bih[nrow] + bhh[nrow]) * s;
    }

    float4v cst[4];

    // --- t = 0: h = c = 0 -> preacts = x*wih_s + b_s (already log2e-scaled) ---
    #pragma unroll
    for (int mt = 0; mt < 4; ++mt) {
        float4v x4 = *(const float4v*)&xt[mt * 16 + quad * 4];
        #pragma unroll
        for (int reg = 0; reg < 4; ++reg) {
            float Bi = ex2(fmaf(x4[reg], wih_v[0], bias_v[0]));
            float Bg = ex2(fmaf(x4[reg], wih_v[2], bias_v[2]));
            float Bo = ex2(fmaf(x4[reg], wih_v[3], bias_v[3]));
            float cn = fmaf(Bi, Bg, -Bi) * rcp_((1.0f + Bi) * (1.0f + Bg));
            cst[mt][reg] = cn;
            float Cc = ex2(cn * L2E2);
            float hv = fmaf(Bo, Cc, -Bo) * rcp_((1.0f + Bo) * (1.0f + Cc));
            hbuf[(mt * 16 + quad * 4 + reg) * HROW + jcol] = (half_t)hv;  // buf 0
        }
    }
    __syncthreads();

    half_t* b0 = hbuf;
    half_t* b1 = hbuf + 64 * HROW;
    // steps 1..6 as 3 double-buffered pairs, step 7 peeled with projection fold
    #pragma unroll 1
    for (int tt = 1; tt < 7; tt += 2) {
        lstm_step<false>(xt + tt * 64,       b0, b1, Bf, wih_v, bias_v, l15, quad, jcol,
                         cst, pW, wpw);
        lstm_step<false>(xt + (tt + 1) * 64, b1, b0, Bf, wih_v, bias_v, l15, quad, jcol,
                         cst, pW, wpw);
    }
    lstm_step<true>(xt + 7 * 64, b0, b1, Bf, wih_v, bias_v, l15, quad, jcol,
                    cst, pW + zbase, wpw);
}

// launch_bounds(256,3): ~170-reg combined budget. R2's spill at (256,3) was with
// the UNCONSTRAINED 4-mt scheduling window (~200+ regs); the sched_barrier
// fence halves the transient window (~160 est). Tripwire: WRITE_SIZE must stay
// ~8 MB — if it blows up, this theory is dead and R0 is final.
extern "C" __global__ void __launch_bounds__(BLOCK, 3) lstm_mfma(
    const float* __restrict__ inputs,
    const float* __restrict__ Wih1, const float* __restrict__ Whh1,
    const float* __restrict__ bih1, const float* __restrict__ bhh1,
    const float* __restrict__ Wih2, const float* __restrict__ Whh2,
    const float* __restrict__ bih2, const float* __restrict__ bhh2,
    const float* __restrict__ pW,
    float* __restrict__ out, int n)
{
    __shared__ half_t hbuf[2 * 64 * HROW];   // 18 KB double-buffered h tile
    __shared__ float  xt_lds[16 * 64];       // x transposed [t][b]
    __shared__ float  wp[4][64][2];          // per-wave projection partials (accumulated)

    const int tid  = threadIdx.x;
    const int w    = tid >> 6;
    const int lane = tid & 63;
    const int base = blockIdx.x * 64;

    // zero wp (4*64*2 = 512 floats) and stage x transposed
    ((float2*)wp)[tid] = make_float2(0.0f, 0.0f);
    for (int idx = tid; idx < 64 * 18; idx += BLOCK) {
        int row = idx / 18, c = idx % 18;
        float v = inputs[(size_t)(base + row) * 18 + c];
        if (c < 16) xt_lds[c * 64 + row] = v;
    }
    __syncthreads();

    float* wpw = &wp[w][0][0];
    lstm_mfma_one(Wih1, Whh1, bih1, bhh1, pW, 0,   xt_lds,          hbuf, w, lane, wpw);
    lstm_mfma_one(Wih2, Whh2, bih2, bhh2, pW, 128, xt_lds + 8 * 64, hbuf, w, lane, wpw);

    // final barrier already executed inside the last lstm_step
    if (tid < 64) {
        int gb = base + tid;
        float2 o = ((float2*)out)[gb];   // MLP kernel ran first on this stream
        o.x += wp[0][tid][0] + wp[1][tid][0] + wp[2][tid][0] + wp[3][tid][0];
        o.y += wp[0][tid][1] + wp[1][tid][1] + wp[2][tid][1] + wp[3][tid][1];
        ((float2*)out)[gb] = o;
    }
}

extern "C" void kernel_launch(void* const* d_in, const int* in_sizes, int n_in,
                              void* d_out, int out_size, void* d_ws, size_t ws_size,
                              hipStream_t stream) {
    const int n = in_sizes[0] / 18;           // 1048576
    mlp_kernel<<<(n + BLOCK - 1) / BLOCK, BLOCK, 0, stream>>>(
        (const float*)d_in[0],
        (const float*)d_in[9],  (const float*)d_in[10],
        (const float*)d_in[11], (const float*)d_in[12],
        (const float*)d_in[13], (const float*)d_in[14],
        (const float*)d_in[15], (const float*)d_in[16],
        (float*)d_out, n);
    lstm_mfma<<<n / 64, BLOCK, 0, stream>>>(
        (const float*)d_in[0],
        (const float*)d_in[1], (const float*)d_in[2],
        (const float*)d_in[3], (const float*)d_in[4],
        (const float*)d_in[5], (const float*)d_in[6],
        (const float*)d_in[7], (const float*)d_in[8],
        (const float*)d_in[15],
        (float*)d_out, n);
}